// Round 1
// baseline (142243.262 us; speedup 1.0000x reference)
//
#include <hip/hip_runtime.h>

// FeedbackTransformerKV — persistent-kernel implementation.
// S=128 steps, strictly sequential via KV memory; per step: 4 transformer
// layers on x[16,512]. One persistent kernel with a custom device-wide
// barrier; phases A(attn) B(out-proj) C(ff1) D(ff2) E(kv+output).

#define S_ 128
#define B_ 16
#define D_ 512
#define H_ 8
#define DK_ 64
#define DFF_ 2048
#define L_ 4
#define P_ 4096

#define NBLK 256
#define NTHR 512

struct FtkvParams {
  const float *x_seq, *w_query, *qpb, *kpe, *w_out, *b_out;
  const float *ln1_g, *ln1_b, *ln2_g, *ln2_b;
  const float *w_ff1, *b_ff1, *w_ff2, *b_ff2;
  const float *norm_g, *norm_b, *comb_w, *w_key, *w_value;
  float *out;
  float *xcur;   // [16][512]
  float *macc;   // [2][16][512]  (double-buffered mem accumulator)
  float *av;     // [16][512]     (attention output, b-major, h*64+d minor)
  float *hbuf;   // [16][2048]    (ff hidden)
  float *memK;   // [16*8][128][64]
  float *memV;   // [16*8][128][64]
  unsigned int *bar; // [0]=arrive, [1]=release
};

__device__ __forceinline__ float waveRedSum(float v) {
#pragma unroll
  for (int off = 32; off; off >>= 1) v += __shfl_xor(v, off, 64);
  return v;
}
__device__ __forceinline__ float waveRedMax(float v) {
#pragma unroll
  for (int off = 32; off; off >>= 1) v = fmaxf(v, __shfl_xor(v, off, 64));
  return v;
}

// Device-wide barrier. All blocks call it the same number of times with the
// same nPart sequence; only blocks with participate==true arrive (producers),
// everyone waits. Monotonic counters, reset by init kernel each launch.
__device__ __forceinline__ void gbar(unsigned int *bar, unsigned int &relIdx,
                                     unsigned int &expArr, bool participate,
                                     int nPart) {
  __syncthreads(); // all block threads done (drains vmem per HIP semantics)
  expArr += (unsigned int)nPart;
  const unsigned int target = relIdx + 1;
  if (threadIdx.x == 0) {
    if (participate) {
      unsigned int a = __hip_atomic_fetch_add(&bar[0], 1u, __ATOMIC_ACQ_REL,
                                              __HIP_MEMORY_SCOPE_AGENT);
      if (a == expArr - 1u) {
        __hip_atomic_store(&bar[1], target, __ATOMIC_RELEASE,
                           __HIP_MEMORY_SCOPE_AGENT);
      }
    }
    while (__hip_atomic_load(&bar[1], __ATOMIC_RELAXED,
                             __HIP_MEMORY_SCOPE_AGENT) < target) {
      __builtin_amdgcn_s_sleep(2);
    }
    __builtin_amdgcn_fence(__ATOMIC_ACQUIRE, "agent");
  }
  relIdx = target;
  __syncthreads();
}

__global__ void ftkv_init(unsigned int *bar) {
  bar[0] = 0u;
  bar[1] = 0u;
}

__global__ __launch_bounds__(NTHR, 2) void ftkv_main(FtkvParams p) {
  const int bid = blockIdx.x;
  const int tid = threadIdx.x;

  __shared__ float sbuf[16 * 516]; // staged 16x512 tiles (pad 516 for banks)
  __shared__ float sred[1088];     // reduction scratch
  __shared__ float sA[384];        // phase A: q[64], qb[64], scores/p[128]

  unsigned int relIdx = 0, expArr = 0;

  // comb = softmax(comb_w) over L+1=5 entries (computed redundantly, cheap)
  float cw0 = p.comb_w[0], cw1 = p.comb_w[1], cw2 = p.comb_w[2],
        cw3 = p.comb_w[3], cw4 = p.comb_w[4];
  float cm = fmaxf(fmaxf(fmaxf(cw0, cw1), fmaxf(cw2, cw3)), cw4);
  float e0 = __expf(cw0 - cm), e1 = __expf(cw1 - cm), e2 = __expf(cw2 - cm),
        e3 = __expf(cw3 - cm), e4 = __expf(cw4 - cm);
  float einv = 1.0f / (e0 + e1 + e2 + e3 + e4);
  float comb0 = e0 * einv, comb1 = e1 * einv, comb2 = e2 * einv,
        comb3 = e3 * einv, comb4 = e4 * einv;

  // INIT: xcur = x_seq[0]; macc[0] = comb0 * x_seq[0]
  for (int i = bid * NTHR + tid; i < B_ * D_; i += NBLK * NTHR) {
    float v = p.x_seq[i];
    p.xcur[i] = v;
    p.macc[i] = comb0 * v;
  }
  gbar(p.bar, relIdx, expArr, true, NBLK);

  for (int t = 0; t < S_; ++t) {
    float *mac = p.macc + (t & 1) * (B_ * D_);
    float *macN = p.macc + ((t + 1) & 1) * (B_ * D_);

    for (int l = 0; l < L_; ++l) {
      const float combl = (l == 0) ? comb1 : (l == 1) ? comb2
                          : (l == 2) ? comb3 : comb4;

      if (t > 0) {
        // ---------------- Phase A: attention per (b,h) ----------------
        if (bid < 128) {
          const int b = bid >> 3, h = bid & 7;
          const int wid = tid >> 6, lane = tid & 63;
          // LN1 of row b (512 elems, one per thread)
          float x0 = p.xcur[b * D_ + tid];
          float s1 = waveRedSum(x0), s2 = waveRedSum(x0 * x0);
          if (lane == 0) { sred[wid] = s1; sred[8 + wid] = s2; }
          __syncthreads();
          if (tid == 0) {
            float a = 0.f, c = 0.f;
            for (int i = 0; i < 8; ++i) { a += sred[i]; c += sred[8 + i]; }
            float mu = a * (1.f / 512.f);
            float var = c * (1.f / 512.f) - mu * mu;
            sred[16] = mu;
            sred[17] = rsqrtf(var + 1e-5f);
          }
          __syncthreads();
          float mu = sred[16], rstd = sred[17];
          sbuf[tid] = (x0 - mu) * rstd * p.ln1_g[l * D_ + tid] +
                      p.ln1_b[l * D_ + tid];
          __syncthreads();
          // q[d] = z . Wq[:, h*64+d]
          {
            int d = tid & 63, ks = tid >> 6; // 8 k-chunks of 64
            const float *wq = p.w_query + (size_t)l * D_ * (H_ * DK_) +
                              h * DK_ + d;
            float acc = 0.f;
            for (int k = ks * 64; k < ks * 64 + 64; ++k)
              acc += sbuf[k] * wq[(size_t)k * (H_ * DK_)];
            sred[tid] = acc;
          }
          __syncthreads();
          if (tid < 64) {
            float q = 0.f;
#pragma unroll
            for (int ks = 0; ks < 8; ++ks) q += sred[tid + 64 * ks];
            sA[tid] = q;                                   // q (for bd term)
            sA[64 + tid] = q + p.qpb[(l * H_ + h) * DK_ + tid]; // q + bias
          }
          __syncthreads();
          // scores[j] = (q+bias).mem_k[j] + q.kpe[P-t+j],  j < t
          {
            int j = tid & 127, ds = tid >> 7; // 4 d-chunks of 16
            float sc = 0.f;
            if (j < t) {
              const float *mk = p.memK + ((size_t)bid * S_ + j) * DK_;
              const float *kp = p.kpe + (size_t)l * P_ * (H_ * DK_) +
                                (size_t)((P_ - t + j) * H_ + h) * DK_;
              for (int d = ds * 16; d < ds * 16 + 16; ++d)
                sc += sA[64 + d] * mk[d] + sA[d] * kp[d];
            }
            sred[tid] = sc;
          }
          __syncthreads();
          if (tid < 128) {
            float sc = (sred[tid] + sred[tid + 128]) +
                       (sred[tid + 256] + sred[tid + 384]);
            sA[128 + tid] = (tid < t) ? sc * 0.125f : -1e30f;
          }
          __syncthreads();
          if (tid < 64) {
            float m = fmaxf(sA[128 + tid], sA[192 + tid]);
            m = waveRedMax(m);
            if (tid == 0) sred[0] = m;
          }
          __syncthreads();
          float mx = sred[0];
          if (tid < 128)
            sA[128 + tid] = (tid < t) ? __expf(sA[128 + tid] - mx) : 0.f;
          __syncthreads();
          if (tid < 64) {
            float s = sA[128 + tid] + sA[192 + tid];
            s = waveRedSum(s);
            if (tid == 0) sred[0] = s;
          }
          __syncthreads();
          float inv = 1.0f / sred[0];
          // av[d] = sum_j p[j] * mem_v[j][d]
          {
            int d = tid & 63, js = tid >> 6; // 8 j-chunks of 16
            float acc = 0.f;
            int j0 = js * 16, j1 = (j0 + 16 < t) ? (j0 + 16) : t;
            for (int j = j0; j < j1; ++j)
              acc += sA[128 + j] * p.memV[((size_t)bid * S_ + j) * DK_ + d];
            sred[tid] = acc;
          }
          __syncthreads();
          if (tid < 64) {
            float a = 0.f;
#pragma unroll
            for (int js = 0; js < 8; ++js) a += sred[tid + 64 * js];
            p.av[b * D_ + h * DK_ + tid] = a * inv;
          }
        }
        gbar(p.bar, relIdx, expArr, bid < 128, 128);

        // ---------------- Phase B: x += av @ W_out + b_out ----------------
        if (bid < 64) {
          for (int i = tid; i < B_ * D_; i += NTHR) {
            int bb = i >> 9, k = i & 511;
            sbuf[bb * 516 + k] = p.av[i];
          }
          __syncthreads();
          int bb = tid & 15, c = (tid >> 4) & 7, ks = tid >> 7; // 4 chunks
          int col = bid * 8 + c;
          const float *wo = p.w_out + (size_t)l * D_ * D_ + col;
          float acc = 0.f;
          for (int k = ks * 128; k < ks * 128 + 128; ++k)
            acc += sbuf[bb * 516 + k] * wo[(size_t)k * D_];
          sred[(tid & 127) * 4 + ks] = acc;
          __syncthreads();
          if (tid < 128) {
            int b2 = tid & 15, c2 = tid >> 4;
            int col2 = bid * 8 + c2;
            float v = sred[tid * 4] + sred[tid * 4 + 1] + sred[tid * 4 + 2] +
                      sred[tid * 4 + 3];
            p.xcur[b2 * D_ + col2] += v + p.b_out[l * D_ + col2];
          }
        }
        gbar(p.bar, relIdx, expArr, bid < 64, 64);
      }

      // ---------------- Phase C: h = relu(LN2(x) @ W1 + b1) ----------------
      {
        for (int i = tid; i < B_ * D_; i += NTHR) {
          int bb = i >> 9, k = i & 511;
          sbuf[bb * 516 + k] = p.xcur[i];
        }
        __syncthreads();
        {
          int r = tid >> 5, ii = tid & 31; // 32 threads per row
          float a = 0.f, c2 = 0.f;
          for (int k = ii * 16; k < ii * 16 + 16; ++k) {
            float v = sbuf[r * 516 + k];
            a += v;
            c2 += v * v;
          }
          sred[tid] = a;
          sred[512 + tid] = c2;
        }
        __syncthreads();
        if (tid < 16) {
          float a = 0.f, c2 = 0.f;
          for (int i = 0; i < 32; ++i) {
            a += sred[tid * 32 + i];
            c2 += sred[512 + tid * 32 + i];
          }
          float mu = a * (1.f / 512.f);
          float var = c2 * (1.f / 512.f) - mu * mu;
          sred[1024 + tid] = mu;
          sred[1056 + tid] = rsqrtf(var + 1e-5f);
        }
        __syncthreads();
        for (int i = tid; i < B_ * D_; i += NTHR) {
          int bb = i >> 9, k = i & 511;
          sbuf[bb * 516 + k] =
              (sbuf[bb * 516 + k] - sred[1024 + bb]) * sred[1056 + bb] *
                  p.ln2_g[l * D_ + k] +
              p.ln2_b[l * D_ + k];
        }
        __syncthreads();
        int bb = tid & 15, c = (tid >> 4) & 7, ks = tid >> 7; // 4 chunks
        int col = bid * 8 + c;
        const float *w1 = p.w_ff1 + (size_t)l * D_ * DFF_ + col;
        float acc = 0.f;
        for (int k = ks * 128; k < ks * 128 + 128; ++k)
          acc += sbuf[bb * 516 + k] * w1[(size_t)k * DFF_];
        sred[(tid & 127) * 4 + ks] = acc;
        __syncthreads();
        if (tid < 128) {
          int b2 = tid & 15, c2 = tid >> 4;
          int col2 = bid * 8 + c2;
          float v = sred[tid * 4] + sred[tid * 4 + 1] + sred[tid * 4 + 2] +
                    sred[tid * 4 + 3] + p.b_ff1[l * DFF_ + col2];
          p.hbuf[b2 * DFF_ + col2] = fmaxf(v, 0.f);
        }
      }
      gbar(p.bar, relIdx, expArr, true, NBLK);

      // ---------------- Phase D: x += h @ W2 + b2; mem += comb*x -----------
      if (bid < 64) {
        int bb = tid & 15, c = (tid >> 4) & 7, ks = tid >> 7;
        int col = bid * 8 + c;
        float acc = 0.f;
        for (int kt = 0; kt < 4; ++kt) {
          __syncthreads();
          for (int i = tid; i < B_ * D_; i += NTHR) {
            int b2 = i >> 9, k = i & 511;
            sbuf[b2 * 516 + k] = p.hbuf[b2 * DFF_ + kt * 512 + k];
          }
          __syncthreads();
          const float *w2 =
              p.w_ff2 + (size_t)l * DFF_ * D_ + (size_t)kt * 512 * D_ + col;
          for (int k = ks * 128; k < ks * 128 + 128; ++k)
            acc += sbuf[bb * 516 + k] * w2[(size_t)k * D_];
        }
        sred[(tid & 127) * 4 + ks] = acc;
        __syncthreads();
        if (tid < 128) {
          int b2 = tid & 15, c2 = tid >> 4;
          int col2 = bid * 8 + c2;
          float v = sred[tid * 4] + sred[tid * 4 + 1] + sred[tid * 4 + 2] +
                    sred[tid * 4 + 3] + p.b_ff2[l * D_ + col2];
          float xn = p.xcur[b2 * D_ + col2] + v;
          p.xcur[b2 * D_ + col2] = xn;
          mac[b2 * D_ + col2] += combl * xn;
        }
      }
      gbar(p.bar, relIdx, expArr, bid < 64, 64);
    } // layers

    // ---------------- Phase E: kv slot t; output row; next x --------------
    if (bid < 128) {
      const int b = bid >> 3, h = bid & 7;
      sbuf[tid] = mac[b * D_ + tid];
      __syncthreads();
      int d = tid & 63, ks = tid >> 6; // 8 k-chunks of 64
      const float *wk = p.w_key + h * DK_ + d;
      const float *wv = p.w_value + h * DK_ + d;
      float ak = 0.f, avv = 0.f;
      for (int k = ks * 64; k < ks * 64 + 64; ++k) {
        float z = sbuf[k];
        ak += z * wk[(size_t)k * (H_ * DK_)];
        avv += z * wv[(size_t)k * (H_ * DK_)];
      }
      sred[tid] = ak;
      sred[512 + tid] = avv;
      __syncthreads();
      if (tid < 64) {
        float a = 0.f, v2 = 0.f;
#pragma unroll
        for (int ks2 = 0; ks2 < 8; ++ks2) {
          a += sred[tid + 64 * ks2];
          v2 += sred[512 + tid + 64 * ks2];
        }
        size_t o = ((size_t)bid * S_ + t) * DK_ + tid;
        p.memK[o] = a;
        p.memV[o] = v2;
      }
    } else if (bid < 144) {
      const int b = bid - 128;
      const int wid = tid >> 6, lane = tid & 63;
      float x0 = p.xcur[b * D_ + tid];
      float s1 = waveRedSum(x0), s2 = waveRedSum(x0 * x0);
      if (lane == 0) { sred[wid] = s1; sred[8 + wid] = s2; }
      __syncthreads();
      if (tid == 0) {
        float a = 0.f, c = 0.f;
        for (int i = 0; i < 8; ++i) { a += sred[i]; c += sred[8 + i]; }
        float mu = a * (1.f / 512.f);
        float var = c * (1.f / 512.f) - mu * mu;
        sred[16] = mu;
        sred[17] = rsqrtf(var + 1e-5f);
      }
      __syncthreads();
      float mu = sred[16], rstd = sred[17];
      p.out[((size_t)t * B_ + b) * D_ + tid] =
          (x0 - mu) * rstd * p.norm_g[tid] + p.norm_b[tid];
      if (t + 1 < S_) {
        float xn = p.x_seq[((size_t)(t + 1) * B_ + b) * D_ + tid];
        p.xcur[b * D_ + tid] = xn;
        macN[b * D_ + tid] = comb0 * xn;
      }
    }
    gbar(p.bar, relIdx, expArr, bid < 144, 144);
  } // t
}

extern "C" void kernel_launch(void *const *d_in, const int *in_sizes, int n_in,
                              void *d_out, int out_size, void *d_ws,
                              size_t ws_size, hipStream_t stream) {
  (void)in_sizes; (void)n_in; (void)out_size; (void)ws_size;

  FtkvParams p;
  p.x_seq  = (const float *)d_in[0];
  p.w_query = (const float *)d_in[1];
  p.qpb    = (const float *)d_in[2];
  p.kpe    = (const float *)d_in[3];
  p.w_out  = (const float *)d_in[4];
  p.b_out  = (const float *)d_in[5];
  p.ln1_g  = (const float *)d_in[6];
  p.ln1_b  = (const float *)d_in[7];
  p.ln2_g  = (const float *)d_in[8];
  p.ln2_b  = (const float *)d_in[9];
  p.w_ff1  = (const float *)d_in[10];
  p.b_ff1  = (const float *)d_in[11];
  p.w_ff2  = (const float *)d_in[12];
  p.b_ff2  = (const float *)d_in[13];
  p.norm_g = (const float *)d_in[14];
  p.norm_b = (const float *)d_in[15];
  p.comb_w = (const float *)d_in[16];
  p.w_key  = (const float *)d_in[17];
  p.w_value = (const float *)d_in[18];
  p.out = (float *)d_out;

  char *ws = (char *)d_ws;
  p.bar = (unsigned int *)ws;
  float *f = (float *)(ws + 256);
  p.xcur = f; f += B_ * D_;          // 8192
  p.macc = f; f += 2 * B_ * D_;      // 16384
  p.av   = f; f += B_ * D_;          // 8192
  p.hbuf = f; f += B_ * DFF_;        // 32768
  p.memK = f; f += B_ * H_ * S_ * DK_; // 1048576
  p.memV = f; f += B_ * H_ * S_ * DK_; // 1048576
  // total ws use: ~8.65 MB

  ftkv_init<<<dim3(1), dim3(1), 0, stream>>>(p.bar);
  ftkv_main<<<dim3(NBLK), dim3(NTHR), 0, stream>>>(p);
}

// Round 2
// 91463.196 us; speedup vs baseline: 1.5552x; 1.5552x over previous
//
#include <hip/hip_runtime.h>

// FeedbackTransformerKV — persistent kernel, round 2.
// Coalesced batched GEMV phases (lane=column), k-split across all 256 blocks,
// fp32 atomic partial combine, precomputed layer-0 q, device-wide barrier.

#define S_ 128
#define B_ 16
#define D_ 512
#define H_ 8
#define DK_ 64
#define DFF_ 2048
#define L_ 4
#define P_ 4096

#define NBLK 256
#define NTHR 512

struct FtkvParams {
  const float *x_seq, *w_query, *qpb, *kpe, *w_out, *b_out;
  const float *ln1_g, *ln1_b, *ln2_g, *ln2_b;
  const float *w_ff1, *b_ff1, *w_ff2, *b_ff2;
  const float *norm_g, *norm_b, *comb_w, *w_key, *w_value;
  float *out;
  float *xcur;   // [16][512]
  float *macc;   // [2][16][512]
  float *av;     // [16][512]
  float *qpart;  // [16 kg][16 b][512]
  float *hbuf4;  // [4 kg][16 b][2048]
  float *memK;   // [128 bh][128 slot][64]
  float *memV;   // [128 bh][128 slot][64]
  float *q0;     // [128 t][16 b][512]
  unsigned int *bar;
};

__device__ __forceinline__ float waveRedSum(float v) {
#pragma unroll
  for (int off = 32; off; off >>= 1) v += __shfl_xor(v, off, 64);
  return v;
}
__device__ __forceinline__ float waveRedMax(float v) {
#pragma unroll
  for (int off = 32; off; off >>= 1) v = fmaxf(v, __shfl_xor(v, off, 64));
  return v;
}

__device__ __forceinline__ void gbar(unsigned int *bar, unsigned int &relIdx,
                                     unsigned int &expArr, bool participate,
                                     int nPart) {
  __syncthreads();
  expArr += (unsigned int)nPart;
  const unsigned int target = relIdx + 1;
  if (threadIdx.x == 0) {
    if (participate) {
      unsigned int a = __hip_atomic_fetch_add(&bar[0], 1u, __ATOMIC_ACQ_REL,
                                              __HIP_MEMORY_SCOPE_AGENT);
      if (a == expArr - 1u) {
        __hip_atomic_store(&bar[1], target, __ATOMIC_RELEASE,
                           __HIP_MEMORY_SCOPE_AGENT);
      }
    }
    while (__hip_atomic_load(&bar[1], __ATOMIC_RELAXED,
                             __HIP_MEMORY_SCOPE_AGENT) < target) {
      __builtin_amdgcn_s_sleep(1);
    }
    __builtin_amdgcn_fence(__ATOMIC_ACQUIRE, "agent");
  }
  relIdx = target;
  __syncthreads();
}

__global__ void ftkv_init(unsigned int *bar) {
  bar[0] = 0u;
  bar[1] = 0u;
}

__global__ __launch_bounds__(NTHR, 4) void ftkv_main(FtkvParams p) {
  const int bid = blockIdx.x;
  const int tid = threadIdx.x;
  const int lane = tid & 63, wid = tid >> 6;

  __shared__ float sX[8192]; // 32KB: staged x (or z rows)
  __shared__ float sZ[2048]; // 8KB: z/h/av k-slice
  __shared__ float sR[1152]; // reduction scratch

  unsigned int relIdx = 0, expArr = 0;

  // comb = softmax(comb_w), 5 entries, computed redundantly
  float cw0 = p.comb_w[0], cw1 = p.comb_w[1], cw2 = p.comb_w[2],
        cw3 = p.comb_w[3], cw4 = p.comb_w[4];
  float cm = fmaxf(fmaxf(fmaxf(cw0, cw1), fmaxf(cw2, cw3)), cw4);
  float e0 = __expf(cw0 - cm), e1 = __expf(cw1 - cm), e2 = __expf(cw2 - cm),
        e3 = __expf(cw3 - cm), e4 = __expf(cw4 - cm);
  float einv = 1.0f / (e0 + e1 + e2 + e3 + e4);
  float comb0 = e0 * einv, comb1 = e1 * einv, comb2 = e2 * einv,
        comb3 = e3 * einv, comb4 = e4 * einv;

  // ---------------- INIT: xcur/macc[0]; precompute q0 for all t -----------
  {
    int i0 = bid * NTHR + tid;
    if (i0 < B_ * D_) {
      float v = p.x_seq[i0];
      p.xcur[i0] = v;
      p.macc[i0] = comb0 * v;
    }
    const int t0 = bid >> 1, brow0 = (bid & 1) * 8;
    for (int i = tid; i < 8 * D_; i += NTHR)
      sX[i] = p.x_seq[(t0 * B_ + brow0 + (i >> 9)) * D_ + (i & 511)];
    __syncthreads();
    if (tid < 256) {
      int r = tid >> 5, ii = tid & 31;
      float a = 0.f, c2 = 0.f;
      for (int k = ii * 16; k < ii * 16 + 16; ++k) {
        float v = sX[r * 512 + k];
        a += v; c2 += v * v;
      }
      sR[tid] = a; sR[256 + tid] = c2;
    }
    __syncthreads();
    if (tid < 8) {
      float a = 0.f, c2 = 0.f;
      for (int i = 0; i < 32; ++i) { a += sR[tid * 32 + i]; c2 += sR[256 + tid * 32 + i]; }
      float mu = a * (1.f / 512.f), var = c2 * (1.f / 512.f) - mu * mu;
      sR[1024 + tid] = mu; sR[1032 + tid] = rsqrtf(var + 1e-5f);
    }
    __syncthreads();
    for (int i = tid; i < 8 * D_; i += NTHR) {
      int r = i >> 9, k = i & 511;
      sX[i] = (sX[i] - sR[1024 + r]) * sR[1032 + r] * p.ln1_g[k] + p.ln1_b[k];
    }
    __syncthreads();
    {
      float acc[8] = {0.f, 0.f, 0.f, 0.f, 0.f, 0.f, 0.f, 0.f};
      for (int k = 0; k < D_; ++k) {
        float w = p.w_query[k * 512 + tid];
#pragma unroll
        for (int b8 = 0; b8 < 8; ++b8) acc[b8] += sX[b8 * 512 + k] * w;
      }
#pragma unroll
      for (int b8 = 0; b8 < 8; ++b8)
        p.q0[((t0 * B_) + brow0 + b8) * D_ + tid] = acc[b8];
    }
  }
  gbar(p.bar, relIdx, expArr, true, NBLK);

  for (int t = 0; t < S_; ++t) {
    float *mac  = p.macc + (t & 1) * (B_ * D_);
    float *macN = p.macc + ((t + 1) & 1) * (B_ * D_);

    for (int l = 0; l < L_; ++l) {
      const float combl = (l == 1) ? comb1 : (l == 2) ? comb2 : comb3;

      // ---- A1 (l>=1): LN1 + qproj partials + macc add ----
      if (l > 0) {
        const int cg = bid >> 4, kg = bid & 15;
        const int k0 = kg * 32, c = tid & 31, b = tid >> 5;
        const int col = cg * 32 + c;
        for (int i = tid; i < B_ * D_; i += NTHR) sX[i] = p.xcur[i];
        __syncthreads();
        {
          int r = tid >> 5, ii = tid & 31;
          float a = 0.f, c2 = 0.f;
          for (int k = ii * 16; k < ii * 16 + 16; ++k) {
            float v = sX[r * 512 + k]; a += v; c2 += v * v;
          }
          sR[tid] = a; sR[512 + tid] = c2;
        }
        __syncthreads();
        if (tid < 16) {
          float a = 0.f, c2 = 0.f;
          for (int i = 0; i < 32; ++i) { a += sR[tid * 32 + i]; c2 += sR[512 + tid * 32 + i]; }
          float mu = a * (1.f / 512.f), var = c2 * (1.f / 512.f) - mu * mu;
          sR[1024 + tid] = mu; sR[1040 + tid] = rsqrtf(var + 1e-5f);
        }
        __syncthreads();
        if (cg == 0) { // macc += comb[l] * x (owner: this kg's 32-k slice)
          int b2 = tid >> 5, k = k0 + (tid & 31);
          mac[b2 * 512 + k] += combl * sX[b2 * 512 + k];
        }
        {
          int b2 = tid >> 5, kk = tid & 31, k = k0 + kk;
          sZ[tid] = (sX[b2 * 512 + k] - sR[1024 + b2]) * sR[1040 + b2] *
                        p.ln1_g[l * 512 + k] + p.ln1_b[l * 512 + k];
        }
        __syncthreads();
        {
          float acc = 0.f;
          const float *wq = p.w_query + (l * 512 + k0) * 512 + col;
          for (int kk = 0; kk < 32; ++kk) acc += sZ[b * 32 + kk] * wq[kk * 512];
          p.qpart[(kg * B_ + b) * D_ + col] = acc;
        }
        gbar(p.bar, relIdx, expArr, true, NBLK);
      }

      if (t > 0) {
        // ---- A2: attention per (b,h); blocks 128-143 refresh xcur (l==0) --
        if (bid < 128) {
          const int b = bid >> 3, h = bid & 7;
          if (tid < 64) {
            float q;
            if (l == 0) {
              q = p.q0[(t * B_ + b) * D_ + h * 64 + tid];
            } else {
              q = 0.f;
              for (int kg = 0; kg < 16; ++kg)
                q += p.qpart[(kg * B_ + b) * D_ + h * 64 + tid];
            }
            sR[tid] = q;
            sR[64 + tid] = q + p.qpb[(l * H_ + h) * 64 + tid];
          }
          __syncthreads();
          {
            float qr = sR[lane], qb = sR[64 + lane];
            for (int jj = 0; jj < 16; ++jj) {
              int j = wid * 16 + jj;
              if (j < t) {
                float mk = p.memK[(bid * S_ + j) * 64 + lane];
                float kp = p.kpe[((l * P_ + (P_ - t + j)) * H_ + h) * 64 + lane];
                float s = waveRedSum(qb * mk + qr * kp);
                if (lane == 0) sR[128 + j] = s;
              }
            }
          }
          __syncthreads();
          if (tid < 128) sR[256 + tid] = (tid < t) ? sR[128 + tid] * 0.125f : -1e30f;
          __syncthreads();
          if (tid < 64) {
            float m = waveRedMax(fmaxf(sR[256 + tid], sR[320 + tid]));
            if (tid == 0) sR[448] = m;
          }
          __syncthreads();
          if (tid < 128)
            sR[256 + tid] = (tid < t) ? __expf(sR[256 + tid] - sR[448]) : 0.f;
          __syncthreads();
          if (tid < 64) {
            float s = waveRedSum(sR[256 + tid] + sR[320 + tid]);
            if (tid == 0) sR[449] = s;
          }
          __syncthreads();
          {
            float inv = 1.0f / sR[449];
            int d = tid & 63, js = tid >> 6;
            int j0 = js * 16, j1 = (j0 + 16 < t) ? (j0 + 16) : t;
            float acc = 0.f;
            for (int j = j0; j < j1; ++j)
              acc += sR[256 + j] * p.memV[(bid * S_ + j) * 64 + d];
            sR[512 + tid] = acc;
            __syncthreads();
            if (tid < 64) {
              float a = 0.f;
#pragma unroll
              for (int js2 = 0; js2 < 8; ++js2) a += sR[512 + js2 * 64 + tid];
              p.av[b * D_ + h * 64 + tid] = a * inv;
            }
          }
        } else if (bid < 144 && l == 0) {
          const int b2 = bid - 128; // refresh x for this step
          p.xcur[b2 * D_ + tid] = p.x_seq[(t * B_ + b2) * D_ + tid];
        }
        gbar(p.bar, relIdx, expArr, bid < ((l == 0) ? 144 : 128),
             (l == 0) ? 144 : 128);

        // ---- B: x += av @ W_out + b_out ----
        {
          const int cg = bid >> 4, kg = bid & 15;
          const int k0 = kg * 32, c = tid & 31, b = tid >> 5;
          const int col = cg * 32 + c;
          sZ[tid] = p.av[b * D_ + k0 + c];
          __syncthreads();
          float acc = 0.f;
          const float *wo = p.w_out + (l * 512 + k0) * 512 + col;
          for (int kk = 0; kk < 32; ++kk) acc += sZ[b * 32 + kk] * wo[kk * 512];
          if (kg == 0) acc += p.b_out[l * 512 + col];
          atomicAdd(&p.xcur[b * D_ + col], acc);
        }
        gbar(p.bar, relIdx, expArr, true, NBLK);
      }

      // ---- C: LN2 + FF1 partials ----
      {
        const int cg = bid >> 2, kg = bid & 3;
        const int k0 = kg * 128, c = tid & 31, b = tid >> 5;
        const int col = cg * 32 + c;
        for (int i = tid; i < B_ * D_; i += NTHR) sX[i] = p.xcur[i];
        __syncthreads();
        {
          int r = tid >> 5, ii = tid & 31;
          float a = 0.f, c2 = 0.f;
          for (int k = ii * 16; k < ii * 16 + 16; ++k) {
            float v = sX[r * 512 + k]; a += v; c2 += v * v;
          }
          sR[tid] = a; sR[512 + tid] = c2;
        }
        __syncthreads();
        if (tid < 16) {
          float a = 0.f, c2 = 0.f;
          for (int i = 0; i < 32; ++i) { a += sR[tid * 32 + i]; c2 += sR[512 + tid * 32 + i]; }
          float mu = a * (1.f / 512.f), var = c2 * (1.f / 512.f) - mu * mu;
          sR[1024 + tid] = mu; sR[1040 + tid] = rsqrtf(var + 1e-5f);
        }
        __syncthreads();
        for (int i = tid; i < 2048; i += NTHR) {
          int b2 = i >> 7, kk = i & 127, k = k0 + kk;
          sZ[i] = (sX[b2 * 512 + k] - sR[1024 + b2]) * sR[1040 + b2] *
                      p.ln2_g[l * 512 + k] + p.ln2_b[l * 512 + k];
        }
        __syncthreads();
        float acc = 0.f;
        const float *w1 = p.w_ff1 + (l * 512 + k0) * 2048 + col;
        for (int kk = 0; kk < 128; ++kk) acc += sZ[b * 128 + kk] * w1[kk * 2048];
        p.hbuf4[(kg * B_ + b) * DFF_ + col] = acc;
      }
      gbar(p.bar, relIdx, expArr, true, NBLK);

      // ---- D: x += relu(h) @ W2 + b2 ----
      {
        const int cg = bid >> 4, kg = bid & 15;
        const int k0 = kg * 128, c = tid & 31, b = tid >> 5;
        const int col = cg * 32 + c;
        for (int i = tid; i < 2048; i += NTHR) {
          int b2 = i >> 7, kk = i & 127, k = k0 + kk;
          float v = p.b_ff1[l * DFF_ + k] +
                    p.hbuf4[(0 * B_ + b2) * DFF_ + k] +
                    p.hbuf4[(1 * B_ + b2) * DFF_ + k] +
                    p.hbuf4[(2 * B_ + b2) * DFF_ + k] +
                    p.hbuf4[(3 * B_ + b2) * DFF_ + k];
          sZ[i] = fmaxf(v, 0.f);
        }
        __syncthreads();
        float acc = 0.f;
        const float *w2 = p.w_ff2 + (l * DFF_ + k0) * 512 + col;
        for (int kk = 0; kk < 128; ++kk) acc += sZ[b * 128 + kk] * w2[kk * 512];
        if (kg == 0) acc += p.b_ff2[l * 512 + col];
        atomicAdd(&p.xcur[b * D_ + col], acc);
      }
      gbar(p.bar, relIdx, expArr, true, NBLK);
    } // layers

    // ---- E: KV slot t (blocks 0-127); out[t] + macc-next (128-143) ----
    if (bid < 128) {
      const int b = bid >> 3, h = bid & 7;
      sX[tid] = mac[b * D_ + tid] + comb4 * p.xcur[b * D_ + tid];
      __syncthreads();
      int d = tid & 63, ks = tid >> 6;
      const float *wk = p.w_key + h * 64 + d;
      const float *wv = p.w_value + h * 64 + d;
      float ak = 0.f, av2 = 0.f;
      for (int k = ks * 64; k < ks * 64 + 64; ++k) {
        float z = sX[k];
        ak += z * wk[k * 512];
        av2 += z * wv[k * 512];
      }
      sR[tid] = ak; sR[512 + tid] = av2;
      __syncthreads();
      if (tid < 64) {
        float a = 0.f, v2 = 0.f;
#pragma unroll
        for (int ks2 = 0; ks2 < 8; ++ks2) {
          a += sR[ks2 * 64 + tid];
          v2 += sR[512 + ks2 * 64 + tid];
        }
        int o = (bid * S_ + t) * 64 + tid;
        p.memK[o] = a; p.memV[o] = v2;
      }
    } else if (bid < 144) {
      const int b2 = bid - 128;
      float x0 = p.xcur[b2 * D_ + tid];
      float s1 = waveRedSum(x0), s2 = waveRedSum(x0 * x0);
      if (lane == 0) { sR[wid] = s1; sR[8 + wid] = s2; }
      __syncthreads();
      if (tid == 0) {
        float a = 0.f, c = 0.f;
        for (int i = 0; i < 8; ++i) { a += sR[i]; c += sR[8 + i]; }
        float mu = a * (1.f / 512.f), var = c * (1.f / 512.f) - mu * mu;
        sR[16] = mu; sR[17] = rsqrtf(var + 1e-5f);
      }
      __syncthreads();
      p.out[(t * B_ + b2) * D_ + tid] =
          (x0 - sR[16]) * sR[17] * p.norm_g[tid] + p.norm_b[tid];
      if (t + 1 < S_)
        macN[b2 * D_ + tid] = comb0 * p.x_seq[((t + 1) * B_ + b2) * D_ + tid];
    }
    gbar(p.bar, relIdx, expArr, bid < 144, 144);
  } // t
}

extern "C" void kernel_launch(void *const *d_in, const int *in_sizes, int n_in,
                              void *d_out, int out_size, void *d_ws,
                              size_t ws_size, hipStream_t stream) {
  (void)in_sizes; (void)n_in; (void)out_size; (void)ws_size;

  FtkvParams p;
  p.x_seq  = (const float *)d_in[0];
  p.w_query = (const float *)d_in[1];
  p.qpb    = (const float *)d_in[2];
  p.kpe    = (const float *)d_in[3];
  p.w_out  = (const float *)d_in[4];
  p.b_out  = (const float *)d_in[5];
  p.ln1_g  = (const float *)d_in[6];
  p.ln1_b  = (const float *)d_in[7];
  p.ln2_g  = (const float *)d_in[8];
  p.ln2_b  = (const float *)d_in[9];
  p.w_ff1  = (const float *)d_in[10];
  p.b_ff1  = (const float *)d_in[11];
  p.w_ff2  = (const float *)d_in[12];
  p.b_ff2  = (const float *)d_in[13];
  p.norm_g = (const float *)d_in[14];
  p.norm_b = (const float *)d_in[15];
  p.comb_w = (const float *)d_in[16];
  p.w_key  = (const float *)d_in[17];
  p.w_value = (const float *)d_in[18];
  p.out = (float *)d_out;

  char *ws = (char *)d_ws;
  p.bar = (unsigned int *)ws;
  float *f = (float *)(ws + 256);
  p.xcur  = f; f += B_ * D_;            // 8192
  p.macc  = f; f += 2 * B_ * D_;        // 16384
  p.av    = f; f += B_ * D_;            // 8192
  p.qpart = f; f += 16 * B_ * D_;       // 131072
  p.hbuf4 = f; f += 4 * B_ * DFF_;      // 131072
  p.memK  = f; f += 128 * S_ * DK_;     // 1048576
  p.memV  = f; f += 128 * S_ * DK_;     // 1048576
  p.q0    = f; f += S_ * B_ * D_;       // 1048576
  // total ≈ 13.8 MB of d_ws

  ftkv_init<<<dim3(1), dim3(1), 0, stream>>>(p.bar);
  ftkv_main<<<dim3(NBLK), dim3(NTHR), 0, stream>>>(p);
}

// Round 3
// 78584.570 us; speedup vs baseline: 1.8101x; 1.1639x over previous
//
#include <hip/hip_runtime.h>

// FeedbackTransformerKV — persistent kernel, round 3.
// Key change vs round 2: NO agent acquire fences (they invalidate per-XCD L2
// and evicted all weights every phase). Cross-block activation data uses
// per-access coherent atomics (sc1, MALL coherence point); weights/kpe use
// normal cached loads and stay L2-resident across all 128 steps.

#define S_ 128
#define B_ 16
#define D_ 512
#define H_ 8
#define DK_ 64
#define DFF_ 2048
#define L_ 4
#define P_ 4096

#define NBLK 256
#define NTHR 512

struct FtkvParams {
  const float *x_seq, *w_query, *qpb, *kpe, *w_out, *b_out;
  const float *ln1_g, *ln1_b, *ln2_g, *ln2_b;
  const float *w_ff1, *b_ff1, *w_ff2, *b_ff2;
  const float *norm_g, *norm_b, *comb_w, *w_key, *w_value;
  float *out;
  float *xcur;   // [16][512]
  float *macc;   // [2][16][512]
  float *av;     // [16][512]
  float *hbuf4;  // [4 kg][16 b][2048]
  float *memK;   // [128 bh][128 slot][64]
  float *memV;   // [128 bh][128 slot][64]
  float *q0;     // [128 t][16 b][512]
  unsigned int *bar;
};

__device__ __forceinline__ float cload(const float *p_) {
  return __hip_atomic_load(p_, __ATOMIC_RELAXED, __HIP_MEMORY_SCOPE_AGENT);
}
__device__ __forceinline__ void cstore(float *p_, float v) {
  __hip_atomic_store(p_, v, __ATOMIC_RELAXED, __HIP_MEMORY_SCOPE_AGENT);
}

__device__ __forceinline__ float waveRedSum(float v) {
#pragma unroll
  for (int off = 32; off; off >>= 1) v += __shfl_xor(v, off, 64);
  return v;
}
__device__ __forceinline__ float waveRedMax(float v) {
#pragma unroll
  for (int off = 32; off; off >>= 1) v = fmaxf(v, __shfl_xor(v, off, 64));
  return v;
}

// Device-wide barrier, NO acquire fence (keeps L2 warm). Producers' shared
// writes are sc1 write-through; __syncthreads drains vmcnt (ack at coherence
// point); arrive is a RELEASE add; waiters spin RELAXED. Consumers read
// shared data with coherent (sc1) loads, so no invalidate is needed.
__device__ __forceinline__ void gbar(unsigned int *bar, unsigned int &relIdx,
                                     unsigned int &expArr, bool participate,
                                     int nPart) {
  __syncthreads();
  expArr += (unsigned int)nPart;
  const unsigned int target = relIdx + 1;
  if (threadIdx.x == 0) {
    if (participate) {
      unsigned int a = __hip_atomic_fetch_add(&bar[0], 1u, __ATOMIC_RELEASE,
                                              __HIP_MEMORY_SCOPE_AGENT);
      if (a == expArr - 1u) {
        __hip_atomic_store(&bar[1], target, __ATOMIC_RELAXED,
                           __HIP_MEMORY_SCOPE_AGENT);
      }
    }
    while (__hip_atomic_load(&bar[1], __ATOMIC_RELAXED,
                             __HIP_MEMORY_SCOPE_AGENT) < target) {
      __builtin_amdgcn_s_sleep(1);
    }
  }
  relIdx = target;
  __syncthreads();
}

__global__ void ftkv_init(unsigned int *bar) {
  bar[0] = 0u;
  bar[1] = 0u;
}

__global__ __launch_bounds__(NTHR, 2) void ftkv_main(FtkvParams p) {
  const int bid = blockIdx.x;
  const int tid = threadIdx.x;
  const int lane = tid & 63, wid = tid >> 6;

  __shared__ float sX[8192];
  __shared__ float sZ[2048];
  __shared__ float sR[1152];

  unsigned int relIdx = 0, expArr = 0;

  // comb = softmax(comb_w), 5 entries
  float cw0 = p.comb_w[0], cw1 = p.comb_w[1], cw2 = p.comb_w[2],
        cw3 = p.comb_w[3], cw4 = p.comb_w[4];
  float cm = fmaxf(fmaxf(fmaxf(cw0, cw1), fmaxf(cw2, cw3)), cw4);
  float e0 = __expf(cw0 - cm), e1 = __expf(cw1 - cm), e2 = __expf(cw2 - cm),
        e3 = __expf(cw3 - cm), e4 = __expf(cw4 - cm);
  float einv = 1.0f / (e0 + e1 + e2 + e3 + e4);
  float comb0 = e0 * einv, comb1 = e1 * einv, comb2 = e2 * einv,
        comb3 = e3 * einv, comb4 = e4 * einv;

  // ---------------- INIT: xcur/macc[0]; q0 for all t ----------------------
  {
    int i0 = bid * NTHR + tid;
    if (i0 < B_ * D_) {
      float v = p.x_seq[i0];
      cstore(&p.xcur[i0], v);
      cstore(&p.macc[i0], comb0 * v);
    }
    const int t0 = bid >> 1, brow0 = (bid & 1) * 8;
    for (int i = tid; i < 8 * D_; i += NTHR)
      sX[i] = p.x_seq[((size_t)t0 * B_ + brow0 + (i >> 9)) * D_ + (i & 511)];
    __syncthreads();
    if (tid < 256) {
      int r = tid >> 5, ii = tid & 31;
      float a = 0.f, c2 = 0.f;
      for (int s = 0; s < 16; ++s) {
        float v = sX[r * 512 + ii + s * 32];
        a += v; c2 += v * v;
      }
      sR[tid] = a; sR[256 + tid] = c2;
    }
    __syncthreads();
    if (tid < 8) {
      float a = 0.f, c2 = 0.f;
      for (int i = 0; i < 32; ++i) { a += sR[tid * 32 + i]; c2 += sR[256 + tid * 32 + i]; }
      float mu = a * (1.f / 512.f), var = c2 * (1.f / 512.f) - mu * mu;
      sR[1024 + tid] = mu; sR[1032 + tid] = rsqrtf(var + 1e-5f);
    }
    __syncthreads();
    for (int i = tid; i < 8 * D_; i += NTHR) {
      int r = i >> 9, k = i & 511;
      sX[i] = (sX[i] - sR[1024 + r]) * sR[1032 + r] * p.ln1_g[k] + p.ln1_b[k];
    }
    __syncthreads();
    {
      float acc[8] = {0.f, 0.f, 0.f, 0.f, 0.f, 0.f, 0.f, 0.f};
      for (int k = 0; k < D_; ++k) {
        float w = p.w_query[k * 512 + tid];
#pragma unroll
        for (int b8 = 0; b8 < 8; ++b8) acc[b8] += sX[b8 * 512 + k] * w;
      }
#pragma unroll
      for (int b8 = 0; b8 < 8; ++b8)
        cstore(&p.q0[((size_t)t0 * B_ + brow0 + b8) * D_ + tid], acc[b8]);
    }
  }
  gbar(p.bar, relIdx, expArr, true, NBLK);

  for (int t = 0; t < S_; ++t) {
    float *mac  = p.macc + (t & 1) * (B_ * D_);
    float *macN = p.macc + ((t + 1) & 1) * (B_ * D_);

    for (int l = 0; l < L_; ++l) {
      const float combl = (l == 1) ? comb1 : (l == 2) ? comb2 : comb3;

      // ---- A2: attention per (b,h) [t>0]; blocks 128-143: refresh / macc --
      if (bid < 128 && t > 0) {
        const int b = bid >> 3, h = bid & 7;
        float qv = 0.f;
        if (l == 0) {
          if (tid < 64)
            qv = cload(&p.q0[((size_t)t * B_ + b) * D_ + h * 64 + tid]);
        } else {
          // LN1(x[b]) + q projection (64 cols, this head only)
          float x0 = cload(&p.xcur[b * D_ + tid]);
          float s1 = waveRedSum(x0), s2 = waveRedSum(x0 * x0);
          if (lane == 0) { sR[wid] = s1; sR[8 + wid] = s2; }
          __syncthreads();
          if (tid == 0) {
            float a = 0.f, c = 0.f;
            for (int i = 0; i < 8; ++i) { a += sR[i]; c += sR[8 + i]; }
            float mu = a * (1.f / 512.f), var = c * (1.f / 512.f) - mu * mu;
            sR[16] = mu; sR[17] = rsqrtf(var + 1e-5f);
          }
          __syncthreads();
          sX[tid] = (x0 - sR[16]) * sR[17] * p.ln1_g[l * 512 + tid] +
                    p.ln1_b[l * 512 + tid];
          __syncthreads();
          {
            int d = tid & 63, ks = tid >> 6;
            const float *wq =
                p.w_query + ((size_t)(l * 512 + ks * 64)) * 512 + h * 64 + d;
            float acc = 0.f;
            for (int kk = 0; kk < 64; ++kk) acc += sX[ks * 64 + kk] * wq[kk * 512];
            sR[512 + tid] = acc;
          }
          __syncthreads();
          if (tid < 64) {
            float a = 0.f;
#pragma unroll
            for (int j = 0; j < 8; ++j) a += sR[512 + j * 64 + tid];
            qv = a;
          }
        }
        if (tid < 64) {
          sR[tid] = qv;
          sR[64 + tid] = qv + p.qpb[(l * H_ + h) * 64 + tid];
        }
        __syncthreads();
        // scores over memory slots
        {
          float qr = sR[lane], qb = sR[64 + lane];
          for (int jj = 0; jj < 16; ++jj) {
            int j = wid * 16 + jj;
            if (j < t) {
              float mk = cload(&p.memK[((size_t)bid * S_ + j) * 64 + lane]);
              float kp =
                  p.kpe[(((size_t)l * P_ + (P_ - t + j)) * H_ + h) * 64 + lane];
              float s = waveRedSum(qb * mk + qr * kp);
              if (lane == 0) sR[128 + j] = s;
            }
          }
        }
        __syncthreads();
        if (tid < 128)
          sR[256 + tid] = (tid < t) ? sR[128 + tid] * 0.125f : -1e30f;
        __syncthreads();
        if (tid < 64) {
          float m = waveRedMax(fmaxf(sR[256 + tid], sR[320 + tid]));
          if (tid == 0) sR[448] = m;
        }
        __syncthreads();
        if (tid < 128)
          sR[256 + tid] = (tid < t) ? __expf(sR[256 + tid] - sR[448]) : 0.f;
        __syncthreads();
        if (tid < 64) {
          float s = waveRedSum(sR[256 + tid] + sR[320 + tid]);
          if (tid == 0) sR[449] = s;
        }
        __syncthreads();
        {
          float inv = 1.0f / sR[449];
          int d = tid & 63, js = tid >> 6;
          int j0 = js * 16, j1 = (j0 + 16 < t) ? (j0 + 16) : t;
          float acc = 0.f;
          for (int j = j0; j < j1; ++j)
            acc += sR[256 + j] * cload(&p.memV[((size_t)bid * S_ + j) * 64 + d]);
          sR[512 + tid] = acc;
          __syncthreads();
          if (tid < 64) {
            float a = 0.f;
#pragma unroll
            for (int js2 = 0; js2 < 8; ++js2) a += sR[512 + js2 * 64 + tid];
            cstore(&p.av[b * D_ + h * 64 + tid], a * inv);
          }
        }
      } else if (bid >= 128 && bid < 144) {
        const int b2 = bid - 128;
        if (l == 0) {
          cstore(&p.xcur[b2 * D_ + tid],
                 p.x_seq[((size_t)t * B_ + b2) * D_ + tid]);
        } else {
          float xv = cload(&p.xcur[b2 * D_ + tid]);
          float mv = cload(&mac[b2 * D_ + tid]);
          cstore(&mac[b2 * D_ + tid], mv + combl * xv);
        }
      }
      gbar(p.bar, relIdx, expArr, bid < 144, 144);

      // ---- B: x += av @ W_out + b_out [t>0] ----
      if (t > 0) {
        const int cg = bid >> 4, kg = bid & 15;
        const int k0 = kg * 32, c = tid & 31, b = tid >> 5;
        const int col = cg * 32 + c;
        sZ[tid] = cload(&p.av[b * D_ + k0 + c]);
        __syncthreads();
        float acc = 0.f;
        const float *wo = p.w_out + ((size_t)(l * 512 + k0)) * 512 + col;
        for (int kk = 0; kk < 32; ++kk) acc += sZ[b * 32 + kk] * wo[kk * 512];
        if (kg == 0) acc += p.b_out[l * 512 + col];
        atomicAdd(&p.xcur[b * D_ + col], acc);
        gbar(p.bar, relIdx, expArr, true, NBLK);
      }

      // ---- C: LN2 + FF1 partials ----
      {
        for (int i = tid; i < B_ * D_; i += NTHR) sX[i] = cload(&p.xcur[i]);
        __syncthreads();
        {
          int r = tid >> 5, ii = tid & 31;
          float a = 0.f, c2 = 0.f;
          for (int s = 0; s < 16; ++s) {
            float v = sX[r * 512 + ii + s * 32];
            a += v; c2 += v * v;
          }
          sR[tid] = a; sR[512 + tid] = c2;
        }
        __syncthreads();
        if (tid < 16) {
          float a = 0.f, c2 = 0.f;
          for (int i = 0; i < 32; ++i) { a += sR[tid * 32 + i]; c2 += sR[512 + tid * 32 + i]; }
          float mu = a * (1.f / 512.f), var = c2 * (1.f / 512.f) - mu * mu;
          sR[1024 + tid] = mu; sR[1040 + tid] = rsqrtf(var + 1e-5f);
        }
        __syncthreads();
        const int cg = bid >> 2, kg = bid & 3;
        const int k0 = kg * 128, c = tid & 31, b = tid >> 5;
        const int col = cg * 32 + c;
        for (int i = tid; i < 2048; i += NTHR) {
          int b2 = i >> 7, kk = i & 127, k = k0 + kk;
          sZ[i] = (sX[b2 * 512 + k] - sR[1024 + b2]) * sR[1040 + b2] *
                      p.ln2_g[l * 512 + k] + p.ln2_b[l * 512 + k];
        }
        __syncthreads();
        float acc = 0.f;
        const float *w1 = p.w_ff1 + ((size_t)(l * 512 + k0)) * 2048 + col;
        for (int kk = 0; kk < 128; ++kk) acc += sZ[b * 128 + kk] * w1[kk * 2048];
        cstore(&p.hbuf4[((size_t)kg * B_ + b) * DFF_ + col], acc);
      }
      gbar(p.bar, relIdx, expArr, true, NBLK);

      // ---- D: x += relu(h) @ W2 + b2 ----
      {
        const int cg = bid >> 4, kg = bid & 15;
        const int k0 = kg * 128, c = tid & 31, b = tid >> 5;
        const int col = cg * 32 + c;
        for (int i = tid; i < 2048; i += NTHR) {
          int b2 = i >> 7, kk = i & 127, k = k0 + kk;
          float v = p.b_ff1[l * DFF_ + k] +
                    cload(&p.hbuf4[((size_t)0 * B_ + b2) * DFF_ + k]) +
                    cload(&p.hbuf4[((size_t)1 * B_ + b2) * DFF_ + k]) +
                    cload(&p.hbuf4[((size_t)2 * B_ + b2) * DFF_ + k]) +
                    cload(&p.hbuf4[((size_t)3 * B_ + b2) * DFF_ + k]);
          sZ[i] = fmaxf(v, 0.f);
        }
        __syncthreads();
        float acc = 0.f;
        const float *w2 = p.w_ff2 + ((size_t)(l * DFF_ + k0)) * 512 + col;
        for (int kk = 0; kk < 128; ++kk) acc += sZ[b * 128 + kk] * w2[kk * 512];
        if (kg == 0) acc += p.b_ff2[l * 512 + col];
        atomicAdd(&p.xcur[b * D_ + col], acc);
      }
      gbar(p.bar, relIdx, expArr, true, NBLK);
    } // layers

    // ---- E: KV slot t (0-127); final-LN out + next-step macc (128-143) ----
    if (bid < 128) {
      const int b = bid >> 3, h = bid & 7;
      sX[tid] = cload(&mac[b * D_ + tid]) + comb4 * cload(&p.xcur[b * D_ + tid]);
      __syncthreads();
      int d = tid & 63, ks = tid >> 6;
      const float *wk = p.w_key + h * 64 + d;
      const float *wv = p.w_value + h * 64 + d;
      float ak = 0.f, av2 = 0.f;
      for (int k = ks * 64; k < ks * 64 + 64; ++k) {
        float z = sX[k];
        ak += z * wk[k * 512];
        av2 += z * wv[k * 512];
      }
      sR[tid] = ak; sR[512 + tid] = av2;
      __syncthreads();
      if (tid < 64) {
        float a = 0.f, v2 = 0.f;
#pragma unroll
        for (int ks2 = 0; ks2 < 8; ++ks2) {
          a += sR[ks2 * 64 + tid];
          v2 += sR[512 + ks2 * 64 + tid];
        }
        size_t o = ((size_t)bid * S_ + t) * 64 + tid;
        cstore(&p.memK[o], a);
        cstore(&p.memV[o], v2);
      }
    } else if (bid < 144) {
      const int b2 = bid - 128;
      float x0 = cload(&p.xcur[b2 * D_ + tid]);
      float s1 = waveRedSum(x0), s2 = waveRedSum(x0 * x0);
      if (lane == 0) { sR[wid] = s1; sR[8 + wid] = s2; }
      __syncthreads();
      if (tid == 0) {
        float a = 0.f, c = 0.f;
        for (int i = 0; i < 8; ++i) { a += sR[i]; c += sR[8 + i]; }
        float mu = a * (1.f / 512.f), var = c * (1.f / 512.f) - mu * mu;
        sR[16] = mu; sR[17] = rsqrtf(var + 1e-5f);
      }
      __syncthreads();
      p.out[((size_t)t * B_ + b2) * D_ + tid] =
          (x0 - sR[16]) * sR[17] * p.norm_g[tid] + p.norm_b[tid];
      if (t + 1 < S_)
        cstore(&macN[b2 * D_ + tid],
               comb0 * p.x_seq[((size_t)(t + 1) * B_ + b2) * D_ + tid]);
    }
    gbar(p.bar, relIdx, expArr, bid < 144, 144);
  } // t
}

extern "C" void kernel_launch(void *const *d_in, const int *in_sizes, int n_in,
                              void *d_out, int out_size, void *d_ws,
                              size_t ws_size, hipStream_t stream) {
  (void)in_sizes; (void)n_in; (void)out_size; (void)ws_size;

  FtkvParams p;
  p.x_seq  = (const float *)d_in[0];
  p.w_query = (const float *)d_in[1];
  p.qpb    = (const float *)d_in[2];
  p.kpe    = (const float *)d_in[3];
  p.w_out  = (const float *)d_in[4];
  p.b_out  = (const float *)d_in[5];
  p.ln1_g  = (const float *)d_in[6];
  p.ln1_b  = (const float *)d_in[7];
  p.ln2_g  = (const float *)d_in[8];
  p.ln2_b  = (const float *)d_in[9];
  p.w_ff1  = (const float *)d_in[10];
  p.b_ff1  = (const float *)d_in[11];
  p.w_ff2  = (const float *)d_in[12];
  p.b_ff2  = (const float *)d_in[13];
  p.norm_g = (const float *)d_in[14];
  p.norm_b = (const float *)d_in[15];
  p.comb_w = (const float *)d_in[16];
  p.w_key  = (const float *)d_in[17];
  p.w_value = (const float *)d_in[18];
  p.out = (float *)d_out;

  char *ws = (char *)d_ws;
  p.bar = (unsigned int *)ws;
  float *f = (float *)(ws + 256);
  p.xcur  = f; f += B_ * D_;
  p.macc  = f; f += 2 * B_ * D_;
  p.av    = f; f += B_ * D_;
  p.hbuf4 = f; f += 4 * B_ * DFF_;
  p.memK  = f; f += 128 * S_ * DK_;
  p.memV  = f; f += 128 * S_ * DK_;
  p.q0    = f; f += S_ * B_ * D_;

  ftkv_init<<<dim3(1), dim3(1), 0, stream>>>(p.bar);
  ftkv_main<<<dim3(NBLK), dim3(NTHR), 0, stream>>>(p);
}

// Round 4
// 64591.528 us; speedup vs baseline: 2.2022x; 1.2166x over previous
//
#include <hip/hip_runtime.h>

// FeedbackTransformerKV — persistent kernel, round 4.
// Batch dimension is fully independent across the whole scan => 16 groups of
// 16 blocks (one per batch element), each with private group barriers on its
// own cachelines (16 arrivals instead of 256 -> kills same-line RMW
// serialization that made each device-wide barrier ~36us). Phases per layer:
// A' (attn + out-proj into delta), C (LN2+FF1), D (FF2 + x/delta/macc
// writeback). E (KV proj + final-LN out + next-x). xcur double-buffered by
// step parity. All cross-block data via agent-scope (sc1) accesses.

#define S_ 128
#define B_ 16
#define D_ 512
#define H_ 8
#define DK_ 64
#define DFF_ 2048
#define L_ 4
#define P_ 4096

#define NBLK 256
#define NTHR 512
#define GSZ 16

struct FtkvParams {
  const float *x_seq, *w_query, *qpb, *kpe, *w_out, *b_out;
  const float *ln1_g, *ln1_b, *ln2_g, *ln2_b;
  const float *w_ff1, *b_ff1, *w_ff2, *b_ff2;
  const float *norm_g, *norm_b, *comb_w, *w_key, *w_value;
  float *out;
  float *xcur;   // [2][16][512]  step-parity double buffer
  float *macc;   // [2][16][512]
  float *delta;  // [16][512]     attn-output accumulator (zeroed in D)
  float *hbuf;   // [16][2048]
  float *memK;   // [16 b][8 h][128 slot][64]
  float *memV;   // [16 b][8 h][128 slot][64]
  float *q0;     // [128 t][16 b][512]
  unsigned int *bar; // [g*32]=arrive_g, [1024+g*32]=rel_g, [2048]/[2080]=global
};

__device__ __forceinline__ float cload(const float *p_) {
  return __hip_atomic_load(p_, __ATOMIC_RELAXED, __HIP_MEMORY_SCOPE_AGENT);
}
__device__ __forceinline__ void cstore(float *p_, float v) {
  __hip_atomic_store(p_, v, __ATOMIC_RELAXED, __HIP_MEMORY_SCOPE_AGENT);
}

__device__ __forceinline__ float waveRedSum(float v) {
#pragma unroll
  for (int off = 32; off; off >>= 1) v += __shfl_xor(v, off, 64);
  return v;
}
__device__ __forceinline__ float waveRedMax(float v) {
#pragma unroll
  for (int off = 32; off; off >>= 1) v = fmaxf(v, __shfl_xor(v, off, 64));
  return v;
}

// Barrier among n blocks sharing (arr, rel). Monotonic epochs, no acquire
// fence (sc1 data path needs none; keeps L2 warm for weights).
__device__ __forceinline__ void gbarN(unsigned *arr, unsigned *rel,
                                      unsigned &epoch, unsigned n) {
  __syncthreads();
  const unsigned e = ++epoch;
  if (threadIdx.x == 0) {
    unsigned old = __hip_atomic_fetch_add(arr, 1u, __ATOMIC_RELEASE,
                                          __HIP_MEMORY_SCOPE_AGENT);
    if (old == e * n - 1u)
      __hip_atomic_store(rel, e, __ATOMIC_RELAXED, __HIP_MEMORY_SCOPE_AGENT);
    while (__hip_atomic_load(rel, __ATOMIC_RELAXED,
                             __HIP_MEMORY_SCOPE_AGENT) < e)
      __builtin_amdgcn_s_sleep(1);
  }
  __syncthreads();
}

__global__ void ftkv_init(unsigned *bar) {
  for (int i = threadIdx.x; i < 4096; i += 256) bar[i] = 0u;
}

__global__ __launch_bounds__(NTHR, 2) void ftkv_main(FtkvParams p) {
  const int bid = blockIdx.x;
  const int tid = threadIdx.x;
  const int lane = tid & 63, wid = tid >> 6;
  const int g = bid & 15;    // batch element / group id
  const int sub = bid >> 4;  // 0..15 within group

  __shared__ float sX[4096];
  __shared__ float sR[1088];

  unsigned gep = 0, dep = 0;
  unsigned *garr = p.bar + g * 32;
  unsigned *grel = p.bar + 1024 + g * 32;

  // comb = softmax(comb_w), 5 entries
  float cw0 = p.comb_w[0], cw1 = p.comb_w[1], cw2 = p.comb_w[2],
        cw3 = p.comb_w[3], cw4 = p.comb_w[4];
  float cm = fmaxf(fmaxf(fmaxf(cw0, cw1), fmaxf(cw2, cw3)), cw4);
  float e0 = __expf(cw0 - cm), e1 = __expf(cw1 - cm), e2 = __expf(cw2 - cm),
        e3 = __expf(cw3 - cm), e4 = __expf(cw4 - cm);
  float einv = 1.0f / (e0 + e1 + e2 + e3 + e4);
  float comb0 = e0 * einv, comb1 = e1 * einv, comb2 = e2 * einv,
        comb3 = e3 * einv, comb4 = e4 * einv;

  // ---------------- INIT: xcur[0]/macc[0]/delta; q0 for all t -------------
  {
    int i0 = bid * NTHR + tid;
    if (i0 < B_ * D_) {
      float v = p.x_seq[i0];
      cstore(&p.xcur[i0], v);          // parity-0 buffer
      cstore(&p.macc[i0], comb0 * v);  // parity-0 buffer
      cstore(&p.delta[i0], 0.f);
    }
    const int t0 = bid >> 1, brow0 = (bid & 1) * 8;
    for (int i = tid; i < 8 * D_; i += NTHR)
      sX[i] = p.x_seq[((size_t)t0 * B_ + brow0 + (i >> 9)) * D_ + (i & 511)];
    __syncthreads();
    if (tid < 256) {
      int r = tid >> 5, ii = tid & 31;
      float a = 0.f, c2 = 0.f;
      for (int s = 0; s < 16; ++s) {
        float v = sX[r * 512 + ii + s * 32];
        a += v; c2 += v * v;
      }
      sR[tid] = a; sR[256 + tid] = c2;
    }
    __syncthreads();
    if (tid < 8) {
      float a = 0.f, c2 = 0.f;
      for (int i = 0; i < 32; ++i) {
        a += sR[tid * 32 + i]; c2 += sR[256 + tid * 32 + i];
      }
      float mu = a * (1.f / 512.f), var = c2 * (1.f / 512.f) - mu * mu;
      sR[1024 + tid] = mu; sR[1032 + tid] = rsqrtf(var + 1e-5f);
    }
    __syncthreads();
    for (int i = tid; i < 8 * D_; i += NTHR) {
      int r = i >> 9, k = i & 511;
      sX[i] = (sX[i] - sR[1024 + r]) * sR[1032 + r] * p.ln1_g[k] + p.ln1_b[k];
    }
    __syncthreads();
    {
      float acc[8] = {0.f, 0.f, 0.f, 0.f, 0.f, 0.f, 0.f, 0.f};
      for (int k = 0; k < D_; ++k) {
        float w = p.w_query[k * 512 + tid];
#pragma unroll
        for (int b8 = 0; b8 < 8; ++b8) acc[b8] += sX[b8 * 512 + k] * w;
      }
#pragma unroll
      for (int b8 = 0; b8 < 8; ++b8)
        cstore(&p.q0[((size_t)t0 * B_ + brow0 + b8) * D_ + tid], acc[b8]);
    }
  }
  gbarN(p.bar + 2048, p.bar + 2080, dep, NBLK); // one device-wide sync

  for (int t = 0; t < S_; ++t) {
    float *xc   = p.xcur + (t & 1) * (B_ * D_);
    float *xcN  = p.xcur + ((t + 1) & 1) * (B_ * D_);
    float *mac  = p.macc + (t & 1) * (B_ * D_);
    float *macN = p.macc + ((t + 1) & 1) * (B_ * D_);

    for (int l = 0; l < L_; ++l) {
      const float combl1 = (l == 0) ? comb1 : (l == 1) ? comb2
                           : (l == 2) ? comb3 : comb4;

      // ---- A': attention + out-proj into delta (t>0; blocks sub<8) ----
      if (t > 0) {
        if (sub < 8) {
          const int h = sub;
          if (l == 0) {
            if (tid < 64) {
              float qv = cload(&p.q0[((size_t)t * B_ + g) * D_ + h * 64 + tid]);
              sR[tid] = qv;
              sR[64 + tid] = qv + p.qpb[(l * H_ + h) * 64 + tid];
            }
          } else {
            float x0 = cload(&xc[g * D_ + tid]);
            float s1 = waveRedSum(x0), s2 = waveRedSum(x0 * x0);
            if (lane == 0) { sR[wid] = s1; sR[8 + wid] = s2; }
            __syncthreads();
            if (tid == 0) {
              float a = 0.f, c = 0.f;
              for (int i = 0; i < 8; ++i) { a += sR[i]; c += sR[8 + i]; }
              float mu = a * (1.f / 512.f), var = c * (1.f / 512.f) - mu * mu;
              sR[16] = mu; sR[17] = rsqrtf(var + 1e-5f);
            }
            __syncthreads();
            sX[tid] = (x0 - sR[16]) * sR[17] * p.ln1_g[l * D_ + tid] +
                      p.ln1_b[l * D_ + tid];
            __syncthreads();
            {
              int d = tid & 63, ks = tid >> 6;
              const float *wq = p.w_query +
                  ((size_t)(l * D_ + ks * 64)) * 512 + h * 64 + d;
              float acc = 0.f;
              for (int kk = 0; kk < 64; ++kk)
                acc += sX[ks * 64 + kk] * wq[(size_t)kk * 512];
              sR[512 + ks * 64 + d] = acc;
            }
            __syncthreads();
            if (tid < 64) {
              float a = 0.f;
#pragma unroll
              for (int j = 0; j < 8; ++j) a += sR[512 + j * 64 + tid];
              sR[tid] = a;
              sR[64 + tid] = a + p.qpb[(l * H_ + h) * 64 + tid];
            }
          }
          __syncthreads();
          // scores over memory slots j < t
          {
            float qr = sR[lane], qb = sR[64 + lane];
            for (int jj = 0; jj < 16; ++jj) {
              int j = wid * 16 + jj;
              if (j < t) {
                float mk = cload(
                    &p.memK[(((size_t)g * H_ + h) * S_ + j) * 64 + lane]);
                float kp = p.kpe[(((size_t)l * P_ + (P_ - t + j)) * H_ + h) *
                                     64 + lane];
                float s = waveRedSum(qb * mk + qr * kp);
                if (lane == 0) sR[128 + j] = s;
              }
            }
          }
          __syncthreads();
          if (tid < 128)
            sR[256 + tid] = (tid < t) ? sR[128 + tid] * 0.125f : -1e30f;
          __syncthreads();
          if (tid < 64) {
            float m = waveRedMax(fmaxf(sR[256 + tid], sR[320 + tid]));
            if (tid == 0) sR[448] = m;
          }
          __syncthreads();
          if (tid < 128)
            sR[256 + tid] = (tid < t) ? __expf(sR[256 + tid] - sR[448]) : 0.f;
          __syncthreads();
          if (tid < 64) {
            float s = waveRedSum(sR[256 + tid] + sR[320 + tid]);
            if (tid == 0) sR[449] = s;
          }
          __syncthreads();
          {
            int d = tid & 63, js = tid >> 6;
            int j0 = js * 16, j1 = (j0 + 16 < t) ? (j0 + 16) : t;
            float acc = 0.f;
            for (int j = j0; j < j1; ++j)
              acc += sR[256 + j] *
                     cload(&p.memV[(((size_t)g * H_ + h) * S_ + j) * 64 + d]);
            sR[512 + js * 64 + d] = acc;
          }
          __syncthreads();
          if (tid < 64) {
            float a = 0.f;
#pragma unroll
            for (int js2 = 0; js2 < 8; ++js2) a += sR[512 + js2 * 64 + tid];
            sX[1024 + tid] = a / sR[449]; // av_h
          }
          __syncthreads();
          // out-proj: col = tid; accumulate into delta
          {
            float acc = (h == 0) ? p.b_out[l * D_ + tid] : 0.f;
            const float *wo =
                p.w_out + ((size_t)l * D_ + h * 64) * 512 + tid;
            for (int kk = 0; kk < 64; ++kk)
              acc += sX[1024 + kk] * wo[(size_t)kk * 512];
            atomicAdd(&p.delta[g * D_ + tid], acc);
          }
        } else {
          // idle blocks: warm L2 with this block's C-phase W1 slice
          const float *w1 = p.w_ff1 + (size_t)l * D_ * DFF_ + sub * 128;
          float dummy = 0.f;
          for (int i = tid; i < 4096; i += NTHR)
            dummy += w1[(size_t)(i >> 3) * DFF_ + (i & 7) * 16];
          asm volatile("" ::"v"(dummy));
        }
        gbarN(garr, grel, gep, GSZ);
      }

      // ---- C: x~ = xc + delta; LN2; FF1 partial (128 cols/block) ----
      {
        float x0 = cload(&xc[g * D_ + tid]) + cload(&p.delta[g * D_ + tid]);
        float s1 = waveRedSum(x0), s2 = waveRedSum(x0 * x0);
        if (lane == 0) { sR[wid] = s1; sR[8 + wid] = s2; }
        __syncthreads();
        if (tid == 0) {
          float a = 0.f, c = 0.f;
          for (int i = 0; i < 8; ++i) { a += sR[i]; c += sR[8 + i]; }
          float mu = a * (1.f / 512.f), var = c * (1.f / 512.f) - mu * mu;
          sR[16] = mu; sR[17] = rsqrtf(var + 1e-5f);
        }
        __syncthreads();
        sX[tid] = (x0 - sR[16]) * sR[17] * p.ln2_g[l * D_ + tid] +
                  p.ln2_b[l * D_ + tid];
        __syncthreads();
        {
          int c = tid & 127, ks = tid >> 7;
          int col = sub * 128 + c;
          const float *w1 =
              p.w_ff1 + ((size_t)(l * D_ + ks * 128)) * DFF_ + col;
          float acc = 0.f;
          for (int kk = 0; kk < 128; ++kk)
            acc += sX[ks * 128 + kk] * w1[(size_t)kk * DFF_];
          sR[ks * 128 + c] = acc;
        }
        __syncthreads();
        if (tid < 128) {
          float v = sR[tid] + sR[128 + tid] + sR[256 + tid] + sR[384 + tid] +
                    p.b_ff1[l * DFF_ + sub * 128 + tid];
          cstore(&p.hbuf[g * DFF_ + sub * 128 + tid], fmaxf(v, 0.f));
        }
      }
      gbarN(garr, grel, gep, GSZ);

      // ---- D: x = xc + delta + relu(h)@W2 + b2; writeback; macc; zero delta
      {
        for (int i = tid; i < DFF_; i += NTHR)
          sX[i] = cload(&p.hbuf[g * DFF_ + i]);
        __syncthreads();
        int c = tid & 31, ks = tid >> 5;
        int col = sub * 32 + c;
        const float *w2 =
            p.w_ff2 + ((size_t)(l * DFF_ + ks * 128)) * 512 + col;
        float acc = 0.f;
        for (int kk = 0; kk < 128; ++kk)
          acc += sX[ks * 128 + kk] * w2[(size_t)kk * 512];
        sR[ks * 32 + c] = acc;
        __syncthreads();
        if (tid < 32) {
          int col2 = sub * 32 + tid;
          float v = p.b_ff2[l * D_ + col2];
          for (int i = 0; i < 16; ++i) v += sR[i * 32 + tid];
          float xn = cload(&xc[g * D_ + col2]) +
                     cload(&p.delta[g * D_ + col2]) + v;
          cstore(&xc[g * D_ + col2], xn);
          cstore(&p.delta[g * D_ + col2], 0.f);
          float mv = cload(&mac[g * D_ + col2]);
          cstore(&mac[g * D_ + col2], mv + combl1 * xn);
        }
      }
      gbarN(garr, grel, gep, GSZ);
    } // layers

    // ---- E: KV proj of mem; final-LN out[t]; next-x refresh ----
    {
      sX[tid] = cload(&mac[g * D_ + tid]);        // mem
      float x0 = cload(&xc[g * D_ + tid]);
      sX[1024 + tid] = x0;                        // x staged
      float s1 = waveRedSum(x0), s2 = waveRedSum(x0 * x0);
      if (lane == 0) { sR[wid] = s1; sR[8 + wid] = s2; }
      __syncthreads();
      if (tid == 0) {
        float a = 0.f, c = 0.f;
        for (int i = 0; i < 8; ++i) { a += sR[i]; c += sR[8 + i]; }
        float mu = a * (1.f / 512.f), var = c * (1.f / 512.f) - mu * mu;
        sR[16] = mu; sR[17] = rsqrtf(var + 1e-5f);
      }
      __syncthreads();
      {
        int d = tid & 63, ks = tid >> 6;
        int colw = (sub & 7) * 64 + d;
        const float *w = ((sub < 8) ? p.w_key : p.w_value) +
                         ((size_t)ks * 64) * 512 + colw;
        float acc = 0.f;
        for (int kk = 0; kk < 64; ++kk)
          acc += sX[ks * 64 + kk] * w[(size_t)kk * 512];
        sR[512 + ks * 64 + d] = acc;
      }
      __syncthreads();
      if (tid < 64) {
        float a = 0.f;
#pragma unroll
        for (int ks2 = 0; ks2 < 8; ++ks2) a += sR[512 + ks2 * 64 + tid];
        float *dst = (sub < 8) ? p.memK : p.memV;
        cstore(&dst[(((size_t)g * H_ + (sub & 7)) * S_ + t) * 64 + tid], a);
      }
      if (tid < 32) {
        int col2 = sub * 32 + tid;
        float xv = sX[1024 + col2];
        p.out[((size_t)t * B_ + g) * D_ + col2] =
            (xv - sR[16]) * sR[17] * p.norm_g[col2] + p.norm_b[col2];
        if (t + 1 < S_) {
          float xn = p.x_seq[((size_t)(t + 1) * B_ + g) * D_ + col2];
          cstore(&xcN[g * D_ + col2], xn);
          cstore(&macN[g * D_ + col2], comb0 * xn);
        }
      }
    }
    gbarN(garr, grel, gep, GSZ);
  } // t
}

extern "C" void kernel_launch(void *const *d_in, const int *in_sizes, int n_in,
                              void *d_out, int out_size, void *d_ws,
                              size_t ws_size, hipStream_t stream) {
  (void)in_sizes; (void)n_in; (void)out_size; (void)ws_size;

  FtkvParams p;
  p.x_seq  = (const float *)d_in[0];
  p.w_query = (const float *)d_in[1];
  p.qpb    = (const float *)d_in[2];
  p.kpe    = (const float *)d_in[3];
  p.w_out  = (const float *)d_in[4];
  p.b_out  = (const float *)d_in[5];
  p.ln1_g  = (const float *)d_in[6];
  p.ln1_b  = (const float *)d_in[7];
  p.ln2_g  = (const float *)d_in[8];
  p.ln2_b  = (const float *)d_in[9];
  p.w_ff1  = (const float *)d_in[10];
  p.b_ff1  = (const float *)d_in[11];
  p.w_ff2  = (const float *)d_in[12];
  p.b_ff2  = (const float *)d_in[13];
  p.norm_g = (const float *)d_in[14];
  p.norm_b = (const float *)d_in[15];
  p.comb_w = (const float *)d_in[16];
  p.w_key  = (const float *)d_in[17];
  p.w_value = (const float *)d_in[18];
  p.out = (float *)d_out;

  char *ws = (char *)d_ws;
  p.bar = (unsigned int *)ws; // 4096 u32 = 16KB
  float *f = (float *)(ws + 16384);
  p.xcur  = f; f += 2 * B_ * D_;        // 16384
  p.macc  = f; f += 2 * B_ * D_;        // 16384
  p.delta = f; f += B_ * D_;            // 8192
  p.hbuf  = f; f += B_ * DFF_;          // 32768
  p.memK  = f; f += B_ * H_ * S_ * DK_; // 1048576
  p.memV  = f; f += B_ * H_ * S_ * DK_; // 1048576
  p.q0    = f; f += S_ * B_ * D_;       // 1048576
  // total ≈ 12.9 MB of d_ws

  ftkv_init<<<dim3(1), dim3(256), 0, stream>>>(p.bar);
  ftkv_main<<<dim3(NBLK), dim3(NTHR), 0, stream>>>(p);
}

// Round 5
// 15663.023 us; speedup vs baseline: 9.0815x; 4.1238x over previous
//
#include <hip/hip_runtime.h>

// FeedbackTransformerKV — persistent kernel, round 5.
// 128 blocks = (batch g 0..15) x (col-slice cs 0..7). cs == head == XCD
// (bid&7 round-robin): each XCD holds only its 1/8 column slice of all
// weights (~5MB, ~L2-resident, plain cached loads). Each block keeps a FULL
// x/macc copy in registers (redundant but comm-free); attention for head cs
// is fully block-local (memK/V produced & consumed by the same block, plain
// loads). Cross-block traffic = 512-wide Wout/FF partials via sc1 + an
// 8-arrival group barrier. 9 barriers/step, groups fully independent.

#define S_ 128
#define B_ 16
#define D_ 512
#define H_ 8
#define DK_ 64
#define DFF_ 2048
#define L_ 4
#define P_ 4096

#define NBLK 128
#define NTHR 512

struct FtkvParams {
  const float *x_seq, *w_query, *qpb, *kpe, *w_out, *b_out;
  const float *ln1_g, *ln1_b, *ln2_g, *ln2_b;
  const float *w_ff1, *b_ff1, *w_ff2, *b_ff2;
  const float *norm_g, *norm_b, *comb_w, *w_key, *w_value;
  float *out;
  float *dpart;   // [16 g][8 cs][512]  Wout partials
  float *dpart2;  // [16 g][8 cs][512]  FF partials
  float *memK;    // [16 g][8 h][128 slot][64]
  float *memV;    // [16 g][8 h][128 slot][64]
  unsigned int *bar;
};

__device__ __forceinline__ float cload(const float *p_) {
  return __hip_atomic_load(p_, __ATOMIC_RELAXED, __HIP_MEMORY_SCOPE_AGENT);
}
__device__ __forceinline__ void cstore(float *p_, float v) {
  __hip_atomic_store(p_, v, __ATOMIC_RELAXED, __HIP_MEMORY_SCOPE_AGENT);
}

__device__ __forceinline__ float waveRedSum(float v) {
#pragma unroll
  for (int off = 32; off; off >>= 1) v += __shfl_xor(v, off, 64);
  return v;
}
__device__ __forceinline__ float waveRedMax(float v) {
#pragma unroll
  for (int off = 32; off; off >>= 1) v = fmaxf(v, __shfl_xor(v, off, 64));
  return v;
}

// 8-block group barrier, monotonic epochs, no acquire fence (sc1 data path;
// plain-load data is block-private so no invalidate needed -> L2 stays warm).
__device__ __forceinline__ void gbarN(unsigned *arr, unsigned *rel,
                                      unsigned &epoch, unsigned n) {
  __syncthreads();
  const unsigned e = ++epoch;
  if (threadIdx.x == 0) {
    unsigned old = __hip_atomic_fetch_add(arr, 1u, __ATOMIC_RELEASE,
                                          __HIP_MEMORY_SCOPE_AGENT);
    if (old == e * n - 1u)
      __hip_atomic_store(rel, e, __ATOMIC_RELAXED, __HIP_MEMORY_SCOPE_AGENT);
    while (__hip_atomic_load(rel, __ATOMIC_RELAXED,
                             __HIP_MEMORY_SCOPE_AGENT) < e)
      __builtin_amdgcn_s_sleep(1);
  }
  __syncthreads();
}

__global__ void ftkv_init(unsigned *bar) {
  for (int i = threadIdx.x; i < 4096; i += 256) bar[i] = 0u;
}

#define LNSTATS(val, mu_, rs_)                                             \
  {                                                                        \
    float _s1 = waveRedSum(val), _s2 = waveRedSum((val) * (val));          \
    __syncthreads();                                                       \
    if (lane == 0) { sRed[wid] = _s1; sRed[8 + wid] = _s2; }               \
    __syncthreads();                                                       \
    if (tid == 0) {                                                        \
      float _a = 0.f, _c = 0.f;                                            \
      for (int _i = 0; _i < 8; ++_i) { _a += sRed[_i]; _c += sRed[8 + _i];}\
      float _mu = _a * (1.f / 512.f);                                      \
      float _var = _c * (1.f / 512.f) - _mu * _mu;                         \
      sRed[16] = _mu; sRed[17] = rsqrtf(_var + 1e-5f);                     \
    }                                                                      \
    __syncthreads();                                                       \
    mu_ = sRed[16]; rs_ = sRed[17];                                        \
  }

__global__ __launch_bounds__(NTHR, 2) void ftkv_main(FtkvParams p) {
  const int bid = blockIdx.x;
  const int tid = threadIdx.x;
  const int lane = tid & 63, wid = tid >> 6;
  const int g = bid >> 3;  // batch element (group)
  const int cs = bid & 7;  // col-slice == head == XCD (heuristic placement)

  __shared__ float sZ[512];   // z / z2 / mem
  __shared__ float sP[512];   // GEMV partial scratch
  __shared__ float sH[256];   // ff hidden slice
  __shared__ float sQ[64], sQB[64], sS[128], sRed[20];

  unsigned *garr = p.bar + g * 32;
  unsigned *grel = p.bar + 1024 + g * 32;
  unsigned gep = 0;

  // comb = softmax(comb_w), 5 entries
  float cw0 = p.comb_w[0], cw1 = p.comb_w[1], cw2 = p.comb_w[2],
        cw3 = p.comb_w[3], cw4 = p.comb_w[4];
  float cm = fmaxf(fmaxf(fmaxf(cw0, cw1), fmaxf(cw2, cw3)), cw4);
  float e0 = __expf(cw0 - cm), e1 = __expf(cw1 - cm), e2 = __expf(cw2 - cm),
        e3 = __expf(cw3 - cm), e4 = __expf(cw4 - cm);
  float einv = 1.0f / (e0 + e1 + e2 + e3 + e4);
  float comb0 = e0 * einv, comb1 = e1 * einv, comb2 = e2 * einv,
        comb3 = e3 * einv, comb4 = e4 * einv;

  // full-x and full-macc copies, one element per thread (tid == column)
  float xr = p.x_seq[g * D_ + tid];
  float mr = comb0 * xr;

  const float *memKb = p.memK + ((size_t)(g * H_ + cs)) * S_ * DK_;
  const float *memVb = p.memV + ((size_t)(g * H_ + cs)) * S_ * DK_;

  for (int t = 0; t < S_; ++t) {
    for (int l = 0; l < L_; ++l) {
      // =================== Phase A: entry-update + attention ============
      if (l > 0) {
        // x += FF(l-1) partials + b_ff2;  macc += comb[l] * x
        float s = p.b_ff2[(l - 1) * D_ + tid];
#pragma unroll
        for (int c2 = 0; c2 < 8; ++c2)
          s += cload(&p.dpart2[((size_t)g * 8 + c2) * D_ + tid]);
        xr += s;
        const float cl = (l == 1) ? comb1 : (l == 2) ? comb2 : comb3;
        mr += cl * xr;
      }
      if (t > 0) {
        float mu, rs;
        LNSTATS(xr, mu, rs);
        sZ[tid] = (xr - mu) * rs * p.ln1_g[l * D_ + tid] +
                  p.ln1_b[l * D_ + tid];
        __syncthreads();
        // q projection for head cs (cols cs*64..): thread=(ks=wid, d=lane)
        {
          const float *wq = p.w_query +
              ((size_t)l * D_ + wid * 64) * 512 + cs * 64 + lane;
          float acc = 0.f;
          for (int kk = 0; kk < 64; ++kk)
            acc += sZ[wid * 64 + kk] * wq[(size_t)kk * 512];
          sP[tid] = acc;
        }
        __syncthreads();
        if (tid < 64) {
          float q = 0.f;
#pragma unroll
          for (int ks = 0; ks < 8; ++ks) q += sP[ks * 64 + tid];
          sQ[tid] = q;
          sQB[tid] = q + p.qpb[(l * H_ + cs) * 64 + tid];
        }
        __syncthreads();
        // scores: thread=(j=tid&127, ds=tid>>7), 16-dim sub-dot
        {
          int j = tid & 127, ds = tid >> 7;
          float acc = 0.f;
          if (j < t) {
            const float *mk = memKb + (size_t)j * 64 + ds * 16;
            const float *kp = p.kpe +
                (((size_t)l * P_ + (P_ - t + j)) * H_ + cs) * 64 + ds * 16;
            for (int ii = 0; ii < 16; ++ii)
              acc += sQB[ds * 16 + ii] * mk[ii] + sQ[ds * 16 + ii] * kp[ii];
          }
          sP[tid] = acc;
        }
        __syncthreads();
        if (tid < 128) {
          float sc = (sP[tid] + sP[tid + 128]) + (sP[tid + 256] + sP[tid + 384]);
          sS[tid] = (tid < t) ? sc * 0.125f : -1e30f;
        }
        __syncthreads();
        if (tid < 64) {
          float m = waveRedMax(fmaxf(sS[tid], sS[tid + 64]));
          if (tid == 0) sRed[18] = m;
        }
        __syncthreads();
        if (tid < 128)
          sS[tid] = (tid < t) ? __expf(sS[tid] - sRed[18]) : 0.f;
        __syncthreads();
        if (tid < 64) {
          float s = waveRedSum(sS[tid] + sS[tid + 64]);
          if (tid == 0) sRed[19] = s;
        }
        __syncthreads();
        // av: thread=(js=wid, d=lane), 16-j sub-sum
        {
          int j0 = wid * 16, j1 = (j0 + 16 < t) ? (j0 + 16) : t;
          float acc = 0.f;
          const float *mv = memVb + lane;
          for (int j = j0; j < j1; ++j) acc += sS[j] * mv[(size_t)j * 64];
          sP[tid] = acc;
        }
        __syncthreads();
        if (tid < 64) {
          float a = 0.f;
#pragma unroll
          for (int js = 0; js < 8; ++js) a += sP[js * 64 + tid];
          sQ[tid] = a / sRed[19];  // av (head cs), reuse sQ
        }
        __syncthreads();
        // Wout partial: delta[c] = av . Wo[rows cs*64.., c], c = tid
        {
          const float *wo =
              p.w_out + ((size_t)l * D_ + cs * 64) * 512 + tid;
          float acc = 0.f;
          for (int k = 0; k < 64; ++k) acc += sQ[k] * wo[(size_t)k * 512];
          cstore(&p.dpart[((size_t)g * 8 + cs) * D_ + tid], acc);
        }
        gbarN(garr, grel, gep, 8);
      }

      // =================== Phase B: out-proj apply + LN2 + FF ===========
      if (t > 0) {
        float s = p.b_out[l * D_ + tid];
#pragma unroll
        for (int c2 = 0; c2 < 8; ++c2)
          s += cload(&p.dpart[((size_t)g * 8 + c2) * D_ + tid]);
        xr += s;
      }
      {
        float mu, rs;
        LNSTATS(xr, mu, rs);
        sZ[tid] = (xr - mu) * rs * p.ln2_g[l * D_ + tid] +
                  p.ln2_b[l * D_ + tid];
      }
      __syncthreads();
      // FF1 for ff-cols cs*256..cs*256+255: thread=(ks=tid>>8, c=tid&255)
      {
        int c = tid & 255, ks = tid >> 8;
        const float *w1 = p.w_ff1 +
            ((size_t)l * D_ + ks * 256) * DFF_ + cs * 256 + c;
        float acc = 0.f;
        for (int kk = 0; kk < 256; ++kk)
          acc += sZ[ks * 256 + kk] * w1[(size_t)kk * DFF_];
        sP[tid] = acc;
      }
      __syncthreads();
      if (tid < 256) {
        float h = sP[tid] + sP[256 + tid] + p.b_ff1[l * DFF_ + cs * 256 + tid];
        sH[tid] = fmaxf(h, 0.f);
      }
      __syncthreads();
      // FF2 partial over own 256 h-rows, all 512 cols (c = tid)
      {
        const float *w2 = p.w_ff2 +
            ((size_t)l * DFF_ + cs * 256) * 512 + tid;
        float acc = 0.f;
        for (int k = 0; k < 256; ++k) acc += sH[k] * w2[(size_t)k * 512];
        cstore(&p.dpart2[((size_t)g * 8 + cs) * D_ + tid], acc);
      }
      gbarN(garr, grel, gep, 8);
    } // layers

    // =================== Phase E: mem -> KV slot t; out[t]; next x ======
    {
      float s = p.b_ff2[3 * D_ + tid];
#pragma unroll
      for (int c2 = 0; c2 < 8; ++c2)
        s += cload(&p.dpart2[((size_t)g * 8 + c2) * D_ + tid]);
      xr += s;
      mr += comb4 * xr;
      sZ[tid] = mr; // mem vector
    }
    __syncthreads();
    // K and V projections for cols cs*64..: thread=(kv=tid>>8, ks, d)
    {
      int r = tid & 255, kv = tid >> 8;
      int ks = r >> 6, d = r & 63;
      const float *w = (kv ? p.w_value : p.w_key) + cs * 64 + d;
      float acc = 0.f;
      for (int k = ks * 128; k < ks * 128 + 128; ++k)
        acc += sZ[k] * w[(size_t)k * 512];
      sP[tid] = acc;
    }
    __syncthreads();
    if (tid < 128) {
      int kv = tid >> 6, d = tid & 63;
      float v = 0.f;
#pragma unroll
      for (int ks = 0; ks < 4; ++ks) v += sP[kv * 256 + ks * 64 + d];
      float *dst = kv ? p.memV : p.memK;
      dst[((size_t)(g * H_ + cs)) * S_ * DK_ + (size_t)t * 64 + d] = v;
    }
    // final LN -> out[t] (each block writes only its own 64 cols)
    {
      float mu, rs;
      LNSTATS(xr, mu, rs);
      if ((tid >> 6) == cs)
        p.out[((size_t)t * B_ + g) * D_ + tid] =
            (xr - mu) * rs * p.norm_g[tid] + p.norm_b[tid];
    }
    if (t + 1 < S_) {
      xr = p.x_seq[((size_t)(t + 1) * B_ + g) * D_ + tid];
      mr = comb0 * xr;
    }
    gbarN(garr, grel, gep, 8);
  } // t
}

extern "C" void kernel_launch(void *const *d_in, const int *in_sizes, int n_in,
                              void *d_out, int out_size, void *d_ws,
                              size_t ws_size, hipStream_t stream) {
  (void)in_sizes; (void)n_in; (void)out_size; (void)ws_size;

  FtkvParams p;
  p.x_seq  = (const float *)d_in[0];
  p.w_query = (const float *)d_in[1];
  p.qpb    = (const float *)d_in[2];
  p.kpe    = (const float *)d_in[3];
  p.w_out  = (const float *)d_in[4];
  p.b_out  = (const float *)d_in[5];
  p.ln1_g  = (const float *)d_in[6];
  p.ln1_b  = (const float *)d_in[7];
  p.ln2_g  = (const float *)d_in[8];
  p.ln2_b  = (const float *)d_in[9];
  p.w_ff1  = (const float *)d_in[10];
  p.b_ff1  = (const float *)d_in[11];
  p.w_ff2  = (const float *)d_in[12];
  p.b_ff2  = (const float *)d_in[13];
  p.norm_g = (const float *)d_in[14];
  p.norm_b = (const float *)d_in[15];
  p.comb_w = (const float *)d_in[16];
  p.w_key  = (const float *)d_in[17];
  p.w_value = (const float *)d_in[18];
  p.out = (float *)d_out;

  char *ws = (char *)d_ws;
  p.bar = (unsigned int *)ws; // 4096 u32 = 16KB
  float *f = (float *)(ws + 16384);
  p.dpart  = f; f += B_ * 8 * D_;        // 64K floats
  p.dpart2 = f; f += B_ * 8 * D_;        // 64K floats
  p.memK   = f; f += B_ * H_ * S_ * DK_; // 1M floats
  p.memV   = f; f += B_ * H_ * S_ * DK_; // 1M floats
  // total ≈ 8.9 MB of d_ws

  ftkv_init<<<dim3(1), dim3(256), 0, stream>>>(p.bar);
  ftkv_main<<<dim3(NBLK), dim3(NTHR), 0, stream>>>(p);
}